// Round 5
// baseline (177.685 us; speedup 1.0000x reference)
//
#include <hip/hip_runtime.h>

// Problem constants (static in the reference: D1=D2=32, ADD1=ADD2=16, BATCH=8)
constexpr int FOCK_DIM = 4656;          // m*(m+1)/2 with m=96, 2 photons
constexpr int N        = 1024;          // D1*D2
constexpr int ROW_VEC  = FOCK_DIM / 4;  // 1164 float4 per output row
constexpr int B        = 8;             // batch
constexpr unsigned TOTAL4 = (unsigned)B * FOCK_DIM * (unsigned)ROW_VEC; // 43,356,672
constexpr int GRID  = 2048;
constexpr int BLOCK = 256;

typedef float f32x4 __attribute__((ext_vector_type(4)));
typedef int   i32x4 __attribute__((ext_vector_type(4)));

// --- build inverse map: inv[f] = i such that fock_idx[i]==f, else -1 ---
__global__ __launch_bounds__(256) void init_inv_kernel(int* __restrict__ inv) {
    int i = blockIdx.x * 256 + threadIdx.x;
    if (i < FOCK_DIM) inv[i] = -1;
}

__global__ __launch_bounds__(256) void fill_inv_kernel(const int* __restrict__ fock_idx,
                                                       int* __restrict__ inv) {
    int i = blockIdx.x * 256 + threadIdx.x;
    if (i < N) inv[fock_idx[i]] = i;
}

// --- main kernel: flat grid-stride over all output float4s (fill-style) ---
// out[b, r, c] = (inv[r]>=0 && inv[c]>=0) ? in[b, inv[r], inv[c]] : 0
// Store address == flat loop index: a perfectly sequential store sweep, same
// shape as the 6.8 TB/s fillBufferAligned. inv (18.6 KB) is L1-resident;
// inv[r] is wave-uniform except at row-straddling iterations (~5%).
__global__ __launch_bounds__(BLOCK) void flat_scatter_kernel(
    const float* __restrict__ in,
    const int*   __restrict__ inv,
    float*       __restrict__ out) {

    const i32x4* __restrict__ inv4 = reinterpret_cast<const i32x4*>(inv);
    f32x4*       __restrict__ out4 = reinterpret_cast<f32x4*>(out);

    #pragma unroll 2
    for (unsigned f = blockIdx.x * BLOCK + threadIdx.x; f < TOTAL4; f += GRID * BLOCK) {
        const unsigned row = f / ROW_VEC;            // magic-mul div
        const unsigned c4  = f - row * ROW_VEC;
        const unsigned b   = row / FOCK_DIM;         // magic-mul div
        const unsigned r   = row - b * FOCK_DIM;
        const int x = inv[r];                        // L1-resident, quasi-uniform

        f32x4 v = {0.f, 0.f, 0.f, 0.f};
        if (x >= 0) {
            const i32x4 iv = inv4[c4];
            const float* __restrict__ irow = in + ((size_t)b * N + (size_t)x) * N;
            v.x = (iv.x >= 0) ? irow[iv.x] : 0.f;
            v.y = (iv.y >= 0) ? irow[iv.y] : 0.f;
            v.z = (iv.z >= 0) ? irow[iv.z] : 0.f;
            v.w = (iv.w >= 0) ? irow[iv.w] : 0.f;
        }
        out4[f] = v;
    }
}

extern "C" void kernel_launch(void* const* d_in, const int* in_sizes, int n_in,
                              void* d_out, int out_size, void* d_ws, size_t ws_size,
                              hipStream_t stream) {
    const float* in       = (const float*)d_in[0];   // [B, 1024, 1024] fp32
    const int*   fock_idx = (const int*)d_in[1];     // [1024] int32
    float*       out      = (float*)d_out;           // [B, 4656, 4656] fp32
    int*         inv      = (int*)d_ws;              // 4656 int32 scratch

    init_inv_kernel<<<(FOCK_DIM + 255) / 256, 256, 0, stream>>>(inv);
    fill_inv_kernel<<<(N + 255) / 256, 256, 0, stream>>>(fock_idx, inv);
    flat_scatter_kernel<<<GRID, BLOCK, 0, stream>>>(in, inv, out);
}

// Round 6
// 152.905 us; speedup vs baseline: 1.1621x; 1.1621x over previous
//
#include <hip/hip_runtime.h>

// Problem constants (static in the reference: D1=D2=32, ADD1=ADD2=16, BATCH=8)
constexpr int FOCK_DIM = 4656;          // m*(m+1)/2 with m=96, 2 photons
constexpr int N        = 1024;          // D1*D2
constexpr int ROW_VEC  = FOCK_DIM / 4;  // 1164 float4 per output row
constexpr int B        = 8;             // batch
constexpr int NBLK_LIVE = B * N;        // 8192 (b, input-row) blocks
constexpr int NBLK_DEAD = B * FOCK_DIM; // 37248 (b, fock-row) blocks

typedef float f32x4 __attribute__((ext_vector_type(4)));
typedef int   i32x4 __attribute__((ext_vector_type(4)));

// --- build inverse map (dead-row detection only): inv[f] = i or -1 ---
__global__ __launch_bounds__(256) void init_inv_kernel(int* __restrict__ inv) {
    int i = blockIdx.x * 256 + threadIdx.x;
    if (i < FOCK_DIM) inv[i] = -1;
}

__global__ __launch_bounds__(256) void fill_inv_kernel(const int* __restrict__ fock_idx,
                                                       int* __restrict__ inv) {
    int i = blockIdx.x * 256 + threadIdx.x;
    if (i < N) inv[fock_idx[i]] = i;
}

// --- main kernel ---
// Live blocks (first NBLK_LIVE): one per (b, input row i). Build the full
// output row in LDS (zero + scatter via fock_idx), then stream it out with
// sequential ds_read_b128 + coalesced stores (store data resolved early).
// Dead blocks (rest): one per (b, fock row r); early-exit if live, else
// stream constant zeros (identical to the proven R1 dead path).
__global__ __launch_bounds__(256) void scatter_main_kernel(
    const float* __restrict__ in,
    const int*   __restrict__ fock_idx,
    const int*   __restrict__ inv,
    float*       __restrict__ out) {

    const int tid = threadIdx.x;
    int blk = blockIdx.x;

    if (blk < NBLK_LIVE) {
        // ---- live path: (b, i) ----
        const int b = blk >> 10;          // / N
        const int i = blk & (N - 1);

        // issue global loads early; LDS zeroing overlaps their latency
        const f32x4 vin = reinterpret_cast<const f32x4*>(
            in + ((size_t)b * N + (size_t)i) * N)[tid];        // input cols 4t..4t+3
        const i32x4 fc = reinterpret_cast<const i32x4*>(fock_idx)[tid]; // their fock cols
        const int r = fock_idx[i];                              // block-uniform

        __shared__ float ldsrow[FOCK_DIM];
        f32x4* lds4 = reinterpret_cast<f32x4*>(ldsrow);
        const f32x4 z = {0.f, 0.f, 0.f, 0.f};
        #pragma unroll
        for (int c4 = tid; c4 < ROW_VEC; c4 += 256) lds4[c4] = z;
        __syncthreads();

        // scatter 4 input values to (mostly consecutive) fock columns
        ldsrow[fc.x] = vin.x;
        ldsrow[fc.y] = vin.y;
        ldsrow[fc.z] = vin.z;
        ldsrow[fc.w] = vin.w;
        __syncthreads();

        // stream out: sequential conflict-free LDS reads -> coalesced stores
        f32x4* orow = reinterpret_cast<f32x4*>(
            out + ((size_t)b * FOCK_DIM + (size_t)r) * FOCK_DIM);
        for (int c4 = tid; c4 < ROW_VEC; c4 += 256) orow[c4] = lds4[c4];
        return;
    }

    // ---- dead path: (b, r) ----
    blk -= NBLK_LIVE;
    const int b = blk / FOCK_DIM;         // magic-mul
    const int r = blk - b * FOCK_DIM;
    if (inv[r] >= 0) return;              // live row already handled

    f32x4* orow = reinterpret_cast<f32x4*>(
        out + ((size_t)b * FOCK_DIM + (size_t)r) * FOCK_DIM);
    const f32x4 z = {0.f, 0.f, 0.f, 0.f};
    for (int c4 = tid; c4 < ROW_VEC; c4 += 256) orow[c4] = z;
}

extern "C" void kernel_launch(void* const* d_in, const int* in_sizes, int n_in,
                              void* d_out, int out_size, void* d_ws, size_t ws_size,
                              hipStream_t stream) {
    const float* in       = (const float*)d_in[0];   // [B, 1024, 1024] fp32
    const int*   fock_idx = (const int*)d_in[1];     // [1024] int32
    float*       out      = (float*)d_out;           // [B, 4656, 4656] fp32
    int*         inv      = (int*)d_ws;              // 4656 int32 scratch

    init_inv_kernel<<<(FOCK_DIM + 255) / 256, 256, 0, stream>>>(inv);
    fill_inv_kernel<<<(N + 255) / 256, 256, 0, stream>>>(fock_idx, inv);
    scatter_main_kernel<<<NBLK_LIVE + NBLK_DEAD, 256, 0, stream>>>(in, fock_idx, inv, out);
}